// Round 7
// baseline (239.138 us; speedup 1.0000x reference)
//
#include <hip/hip_runtime.h>
#include <hip/hip_cooperative_groups.h>

namespace cg = cooperative_groups;

// MMD loss: source (4096,256) fp32, target (4096,256) fp32 -> scalar fp32.
// bandwidth closed form: sum(l2) = 2n*S - 2*||m||^2 (relu effect negligible).
// ONE cooperative persistent kernel (k_all):
//   Phase A: fp32->bf16 tb, sq[], 8-way split colsum/Ssum atomics
//   grid.sync
//   Phase B: every block computes coef = log2(e)/(16*bw) from partials
//   Phase C: persistent loop over 2080 triangular 128x128 tiles; bf16 MFMA
//            16x16x32, XOR-swizzled global_load_lds w=16, single-buffer BK=64,
//            packed epilogue t+t^2+t^4+t^8+t^16; per-block scalar accumulate
//   grid.sync
//   Phase D: block 0 reduces part[] -> out
// Fallback (coop launch rejected or ws too small): round-6 4-dispatch path.

#define NROWS 8192
#define BHALF 4096
#define DDIM  256
#define TILE  128
#define NTILE 64
#define NBLK  2080   // NTILE*(NTILE+1)/2

typedef __attribute__((ext_vector_type(8))) short bf16x8;
typedef __attribute__((ext_vector_type(4))) float f32x4;
typedef __attribute__((ext_vector_type(2))) float f32x2;
typedef __attribute__((ext_vector_type(4))) unsigned short u16x4;

struct Ws {
  float Ssum8[8];          // -- memset-zeroed region (8224 B) --
  float colsum2[8][256];   // -- end zeroed region --
  float coef;              // fallback path only
  float Spart[256];
  float cpart[256][256];
  float sq[NROWS];
  float part[NBLK];
};

__device__ __forceinline__ unsigned short f2bf(float x) {
  unsigned int u = __builtin_bit_cast(unsigned int, x);
  return (unsigned short)((u + 0x7fffu + ((u >> 16) & 1u)) >> 16);
}

__device__ __forceinline__ const float* row_ptr(const float* src, const float* tgt, int i) {
  return (i < BHALF) ? (src + (size_t)i * DDIM) : (tgt + (size_t)(i - BHALF) * DDIM);
}

__device__ __forceinline__ void stage_panel(const unsigned short* g,
                                            unsigned short* l, int kc) {
  #pragma unroll
  for (int t = 0; t < 4; ++t)
    __builtin_amdgcn_global_load_lds(
        (const __attribute__((address_space(1))) void*)(g + (size_t)(t * 8) * DDIM + kc * 64),
        (__attribute__((address_space(3))) void*)(l + (t * 8) * 64), 16, 0, 0);
}

// ---------------- merged cooperative kernel ----------------
__global__ __launch_bounds__(256, 4) void k_all(const float* __restrict__ src,
                                                const float* __restrict__ tgt,
                                                Ws* __restrict__ ws,
                                                unsigned short* __restrict__ tb,
                                                float* __restrict__ out) {
  __shared__ __align__(16) unsigned short As[TILE * 64];
  __shared__ __align__(16) unsigned short Bs[TILE * 64];
  __shared__ float wsum[4];
  __shared__ float coefS;
  __shared__ double dred[4];

  int tid = threadIdx.x, wave = tid >> 6, lane = tid & 63;

  // ---- Phase A: convert + stats (cls aliases As, sred aliases Bs) ----
  {
    float (*cls)[256] = (float (*)[256])As;
    float* sred = (float*)Bs;
    int W = blockIdx.x * 4 + wave, NW = gridDim.x * 4;
    float c0 = 0.f, c1 = 0.f, c2 = 0.f, c3 = 0.f, Sw = 0.f;
    for (int pr = W; pr < NROWS / 2; pr += NW) {
      #pragma unroll
      for (int r = 0; r < 2; ++r) {
        int row = pr * 2 + r;
        float4 x = ((const float4*)row_ptr(src, tgt, row))[lane];
        u16x4 b = { f2bf(x.x), f2bf(x.y), f2bf(x.z), f2bf(x.w) };
        *(u16x4*)&tb[(size_t)row * DDIM + lane * 4] = b;
        c0 += x.x; c1 += x.y; c2 += x.z; c3 += x.w;
        float s = x.x * x.x + x.y * x.y + x.z * x.z + x.w * x.w;
        #pragma unroll
        for (int off = 32; off > 0; off >>= 1) s += __shfl_xor(s, off);
        if (lane == 0) { ws->sq[row] = s; Sw += s; }
      }
    }
    cls[wave][lane * 4 + 0] = c0;
    cls[wave][lane * 4 + 1] = c1;
    cls[wave][lane * 4 + 2] = c2;
    cls[wave][lane * 4 + 3] = c3;
    if (lane == 0) sred[wave] = Sw;
    __syncthreads();
    atomicAdd(&ws->colsum2[blockIdx.x & 7][tid],
              cls[0][tid] + cls[1][tid] + cls[2][tid] + cls[3][tid]);
    if (tid == 0)
      atomicAdd(&ws->Ssum8[blockIdx.x & 7], sred[0] + sred[1] + sred[2] + sred[3]);
    __syncthreads();                       // done with aliased LDS
  }
  cg::this_grid().sync();

  // ---- Phase B: every block computes coef ----
  {
    float mc = 0.f;
    #pragma unroll
    for (int k = 0; k < 8; ++k) mc += ws->colsum2[k][tid];
    float p = mc * mc;
    #pragma unroll
    for (int off = 32; off > 0; off >>= 1) p += __shfl_xor(p, off);
    if (lane == 0) wsum[wave] = p;
    __syncthreads();
    if (tid == 0) {
      float msq = wsum[0] + wsum[1] + wsum[2] + wsum[3];
      float S = 0.f;
      #pragma unroll
      for (int k = 0; k < 8; ++k) S += ws->Ssum8[k];
      double n = (double)NROWS;
      double sum_l2 = 2.0 * n * (double)S - 2.0 * (double)msq;
      double bwv = sum_l2 / (n * n - n) / 4.0;   // / KERNEL_MUL^(KERNEL_NUM/2)
      coefS = (float)(1.4426950408889634 / (16.0 * bwv)); // log2(e)/(16*bw)
    }
    __syncthreads();
  }
  float coef = coefS;
  float coef2 = 2.f * coef;
  int wm = wave >> 1, wn = wave & 1;             // 2x2 wave grid, 64x64 each
  int lr = lane & 15, q = lane >> 4;
  int lrow = lane >> 3;                          // staging row 0..7
  int lchk = (lane & 7) ^ lrow;                  // XOR-swizzled source chunk
  float blocksum = 0.f;

  // ---- Phase C: persistent tile loop ----
  for (int idx = blockIdx.x; idx < NBLK; idx += gridDim.x) {
    int ti = (int)((129.0 - sqrt(129.0 * 129.0 - 8.0 * (double)idx)) * 0.5);
    while (64 * (ti + 1) - ((ti + 1) * ti) / 2 <= idx) ++ti;
    while (64 * ti - (ti * (ti - 1)) / 2 > idx) --ti;
    int tj = ti + (idx - (64 * ti - (ti * (ti - 1)) / 2));
    int Ib = ti * TILE, Jb = tj * TILE;
    bool diag = (ti == tj);

    // epilogue prefetch: negative coef-scaled row norms
    int ibase = Ib + wm * 64;
    int jbase = Jb + wn * 64;
    float nscj[4];
    f32x2 nsci01[4], nsci23[4];
    #pragma unroll
    for (int n = 0; n < 4; ++n) nscj[n] = -ws->sq[jbase + n * 16 + lr] * coef;
    #pragma unroll
    for (int m = 0; m < 4; ++m) {
      nsci01[m] = f32x2{ -ws->sq[ibase + m * 16 + q * 4 + 0] * coef,
                         -ws->sq[ibase + m * 16 + q * 4 + 1] * coef };
      nsci23[m] = f32x2{ -ws->sq[ibase + m * 16 + q * 4 + 2] * coef,
                         -ws->sq[ibase + m * 16 + q * 4 + 3] * coef };
    }

    f32x4 zero = {0.f, 0.f, 0.f, 0.f};
    f32x4 acc[4][4];
    #pragma unroll
    for (int m = 0; m < 4; ++m)
      #pragma unroll
      for (int n = 0; n < 4; ++n) acc[m][n] = zero;

    const unsigned short* gA = tb + (size_t)(Ib + wave * 32 + lrow) * DDIM + lchk * 8;
    const unsigned short* gB = tb + (size_t)(Jb + wave * 32 + lrow) * DDIM + lchk * 8;
    const unsigned short* Bbase = diag ? As : Bs;

    #pragma unroll
    for (int kc = 0; kc < 4; ++kc) {
      if (kc) __syncthreads();                   // prior compute done before overwrite
      stage_panel(gA, &As[(wave * 32) * 64], kc);
      if (!diag) stage_panel(gB, &Bs[(wave * 32) * 64], kc);
      __syncthreads();                           // staged tile ready (drains vmcnt)
      #pragma unroll
      for (int kk = 0; kk < 2; ++kk) {
        int cidx = ((kk * 4 + q) ^ (lr & 7)) << 3;   // swizzled chunk offset
        bf16x8 af[4], bfr[4];
        #pragma unroll
        for (int m = 0; m < 4; ++m)
          af[m] = *(const bf16x8*)&As[(wm * 64 + m * 16 + lr) * 64 + cidx];
        #pragma unroll
        for (int n = 0; n < 4; ++n)
          bfr[n] = *(const bf16x8*)&Bbase[(wn * 64 + n * 16 + lr) * 64 + cidx];
        #pragma unroll
        for (int m = 0; m < 4; ++m)
          #pragma unroll
          for (int n = 0; n < 4; ++n)
            acc[m][n] = __builtin_amdgcn_mfma_f32_16x16x32_bf16(af[m], bfr[n], acc[m][n], 0, 0, 0);
      }
    }

    // Packed epilogue: arg = 2g*coef - (sqi+sqj)*coef; K = t+t^2+t^4+t^8+t^16.
    const f32x2 c2v = { coef2, coef2 };
    f32x2 accA = {0.f, 0.f}, accB = {0.f, 0.f};
    f32x2 accC = {0.f, 0.f}, accD = {0.f, 0.f};
    #pragma unroll
    for (int m = 0; m < 4; ++m) {
      #pragma unroll
      for (int n = 0; n < 4; ++n) {
        f32x4 g = acc[m][n];
        f32x2 bj = { nscj[n], nscj[n] };
        f32x2 b01 = nsci01[m] + bj;
        f32x2 b23 = nsci23[m] + bj;
        f32x2 a01 = f32x2{g[0], g[1]} * c2v + b01;
        f32x2 a23 = f32x2{g[2], g[3]} * c2v + b23;
        f32x2 t0, t1;
        t0.x = __builtin_amdgcn_exp2f(a01.x); t0.y = __builtin_amdgcn_exp2f(a01.y);
        t1.x = __builtin_amdgcn_exp2f(a23.x); t1.y = __builtin_amdgcn_exp2f(a23.y);
        f32x2 p0 = t0 * t0, p1 = t1 * t1;
        f32x2 q0 = p0 * p0, q1 = p1 * p1;
        f32x2 r0v = q0 * q0, r1v = q1 * q1;
        accA += t0 + p0;
        accB += q0 + r0v;
        accA = r0v * r0v + accA;               // + t^16
        accC += t1 + p1;
        accD += q1 + r1v;
        accC = r1v * r1v + accC;
      }
    }
    float lsum = (accA.x + accA.y) + (accB.x + accB.y)
               + (accC.x + accC.y) + (accD.x + accD.y);
    #pragma unroll
    for (int off = 32; off > 0; off >>= 1) lsum += __shfl_xor(lsum, off);
    if (lane == 0) wsum[wave] = lsum;
    __syncthreads();
    if (tid == 0) {
      float tot = wsum[0] + wsum[1] + wsum[2] + wsum[3];
      float sA = (ti < 32) ? 1.f : -1.f;       // B=4096 = 32 tiles of 128
      float sB = (tj < 32) ? 1.f : -1.f;
      blocksum += sA * sB * ((ti == tj) ? 1.f : 2.f) * tot;
    }
  }
  if (tid == 0) ws->part[blockIdx.x] = blocksum;   // plain store
  cg::this_grid().sync();

  // ---- Phase D: block 0 reduces ----
  if (blockIdx.x == 0) {
    double s = 0.0;
    for (int i = tid; i < (int)gridDim.x; i += 256) s += (double)ws->part[i];
    #pragma unroll
    for (int off = 32; off > 0; off >>= 1) s += __shfl_xor(s, off);
    if (lane == 0) dred[wave] = s;
    __syncthreads();
    if (tid == 0)
      out[0] = (float)((dred[0] + dred[1] + dred[2] + dred[3]) /
                       ((double)BHALF * (double)BHALF));
  }
}

// ---------------- round-6 fallback path ----------------
__global__ __launch_bounds__(256) void k_prep(const float* __restrict__ src,
                                              const float* __restrict__ tgt,
                                              Ws* __restrict__ ws,
                                              unsigned short* __restrict__ tb,
                                              int conv) {
  __shared__ float cls[4][256];
  __shared__ float sred[4];
  int tid = threadIdx.x, wave = tid >> 6, lane = tid & 63;
  int row0 = blockIdx.x * 32 + wave * 8;
  float c0 = 0.f, c1 = 0.f, c2 = 0.f, c3 = 0.f;
  float s[8];
  #pragma unroll
  for (int r = 0; r < 8; ++r) {
    const float4* rp = (const float4*)row_ptr(src, tgt, row0 + r);
    float4 x = rp[lane];
    if (conv) {
      u16x4 b = { f2bf(x.x), f2bf(x.y), f2bf(x.z), f2bf(x.w) };
      *(u16x4*)&tb[(size_t)(row0 + r) * DDIM + lane * 4] = b;
    }
    c0 += x.x; c1 += x.y; c2 += x.z; c3 += x.w;
    s[r] = x.x * x.x + x.y * x.y + x.z * x.z + x.w * x.w;
  }
  #pragma unroll
  for (int off = 32; off > 0; off >>= 1) {
    #pragma unroll
    for (int r = 0; r < 8; ++r) s[r] += __shfl_xor(s[r], off);
  }
  if (lane == 0) {
    float Sw = 0.f;
    #pragma unroll
    for (int r = 0; r < 8; ++r) { ws->sq[row0 + r] = s[r]; Sw += s[r]; }
    sred[wave] = Sw;
  }
  cls[wave][lane * 4 + 0] = c0;
  cls[wave][lane * 4 + 1] = c1;
  cls[wave][lane * 4 + 2] = c2;
  cls[wave][lane * 4 + 3] = c3;
  __syncthreads();
  ws->cpart[blockIdx.x][tid] = cls[0][tid] + cls[1][tid] + cls[2][tid] + cls[3][tid];
  if (tid == 0) ws->Spart[blockIdx.x] = sred[0] + sred[1] + sred[2] + sred[3];
}

__global__ __launch_bounds__(256) void k_bw(Ws* __restrict__ ws) {
  __shared__ float redm[4], reds[4];
  int tid = threadIdx.x, wave = tid >> 6, lane = tid & 63;
  float mc = 0.f;
  for (int b = 0; b < 256; ++b) mc += ws->cpart[b][tid];
  float p = mc * mc;
  float sp = ws->Spart[tid];
  #pragma unroll
  for (int off = 32; off > 0; off >>= 1) {
    p  += __shfl_xor(p, off);
    sp += __shfl_xor(sp, off);
  }
  if (lane == 0) { redm[wave] = p; reds[wave] = sp; }
  __syncthreads();
  if (tid == 0) {
    float msq = redm[0] + redm[1] + redm[2] + redm[3];
    float S   = reds[0] + reds[1] + reds[2] + reds[3];
    double n = (double)NROWS;
    double sum_l2 = 2.0 * n * (double)S - 2.0 * (double)msq;
    double bwv = sum_l2 / (n * n - n) / 4.0;
    ws->coef = (float)(1.4426950408889634 / (16.0 * bwv));
  }
}

template <int FAST>
__global__ __launch_bounds__(256, 4) void k_main(const unsigned short* __restrict__ tb,
                                                 const float* __restrict__ src,
                                                 const float* __restrict__ tgt,
                                                 Ws* __restrict__ ws) {
  int idx = blockIdx.x;
  int ti = (int)((129.0 - sqrt(129.0 * 129.0 - 8.0 * (double)idx)) * 0.5);
  while (64 * (ti + 1) - ((ti + 1) * ti) / 2 <= idx) ++ti;
  while (64 * ti - (ti * (ti - 1)) / 2 > idx) --ti;
  int tj = ti + (idx - (64 * ti - (ti * (ti - 1)) / 2));

  __shared__ __align__(16) unsigned short As[TILE * 64];
  __shared__ __align__(16) unsigned short Bs[TILE * 64];
  __shared__ float wsum[4];

  int tid = threadIdx.x;
  int wave = tid >> 6, lane = tid & 63;
  int wm = wave >> 1, wn = wave & 1;
  int lr = lane & 15, q = lane >> 4;
  int Ib = ti * TILE, Jb = tj * TILE;

  float coef = ws->coef;
  float coef2 = 2.f * coef;
  int ibase = Ib + wm * 64;
  int jbase = Jb + wn * 64;
  float nscj[4];
  f32x2 nsci01[4], nsci23[4];
  #pragma unroll
  for (int n = 0; n < 4; ++n) nscj[n] = -ws->sq[jbase + n * 16 + lr] * coef;
  #pragma unroll
  for (int m = 0; m < 4; ++m) {
    nsci01[m] = f32x2{ -ws->sq[ibase + m * 16 + q * 4 + 0] * coef,
                       -ws->sq[ibase + m * 16 + q * 4 + 1] * coef };
    nsci23[m] = f32x2{ -ws->sq[ibase + m * 16 + q * 4 + 2] * coef,
                       -ws->sq[ibase + m * 16 + q * 4 + 3] * coef };
  }

  f32x4 zero = {0.f, 0.f, 0.f, 0.f};
  f32x4 acc[4][4];
  #pragma unroll
  for (int m = 0; m < 4; ++m)
    #pragma unroll
    for (int n = 0; n < 4; ++n) acc[m][n] = zero;

  const unsigned short* gA = nullptr; const unsigned short* gB = nullptr;
  if (FAST) {
    int lrow = lane >> 3;
    int lchk = (lane & 7) ^ lrow;
    gA = tb + (size_t)(Ib + wave * 32 + lrow) * DDIM + lchk * 8;
    gB = tb + (size_t)(Jb + wave * 32 + lrow) * DDIM + lchk * 8;
  }
  int r0 = tid >> 4, c4 = tid & 15;

  #pragma unroll
  for (int kc = 0; kc < 4; ++kc) {
    if (kc) __syncthreads();
    if (FAST) {
      stage_panel(gA, &As[(wave * 32) * 64], kc);
      stage_panel(gB, &Bs[(wave * 32) * 64], kc);
    } else {
      #pragma unroll
      for (int rr = 0; rr < 8; ++rr) {
        int row = rr * 16 + r0;
        int sw = ((c4 >> 1) ^ (row & 7)) * 8 + (c4 & 1) * 4;
        float4 va = ((const float4*)row_ptr(src, tgt, Ib + row))[kc * 16 + c4];
        u16x4 ba = { f2bf(va.x), f2bf(va.y), f2bf(va.z), f2bf(va.w) };
        *(u16x4*)&As[row * 64 + sw] = ba;
        float4 vb = ((const float4*)row_ptr(src, tgt, Jb + row))[kc * 16 + c4];
        u16x4 bb = { f2bf(vb.x), f2bf(vb.y), f2bf(vb.z), f2bf(vb.w) };
        *(u16x4*)&Bs[row * 64 + sw] = bb;
      }
    }
    __syncthreads();
    #pragma unroll
    for (int kk = 0; kk < 2; ++kk) {
      int cidx = ((kk * 4 + q) ^ (lr & 7)) << 3;
      bf16x8 af[4], bfr[4];
      #pragma unroll
      for (int m = 0; m < 4; ++m)
        af[m] = *(const bf16x8*)&As[(wm * 64 + m * 16 + lr) * 64 + cidx];
      #pragma unroll
      for (int n = 0; n < 4; ++n)
        bfr[n] = *(const bf16x8*)&Bs[(wn * 64 + n * 16 + lr) * 64 + cidx];
      #pragma unroll
      for (int m = 0; m < 4; ++m)
        #pragma unroll
        for (int n = 0; n < 4; ++n)
          acc[m][n] = __builtin_amdgcn_mfma_f32_16x16x32_bf16(af[m], bfr[n], acc[m][n], 0, 0, 0);
    }
  }

  const f32x2 c2v = { coef2, coef2 };
  f32x2 accA = {0.f, 0.f}, accB = {0.f, 0.f};
  f32x2 accC = {0.f, 0.f}, accD = {0.f, 0.f};
  #pragma unroll
  for (int m = 0; m < 4; ++m) {
    #pragma unroll
    for (int n = 0; n < 4; ++n) {
      f32x4 g = acc[m][n];
      f32x2 bj = { nscj[n], nscj[n] };
      f32x2 b01 = nsci01[m] + bj;
      f32x2 b23 = nsci23[m] + bj;
      f32x2 a01 = f32x2{g[0], g[1]} * c2v + b01;
      f32x2 a23 = f32x2{g[2], g[3]} * c2v + b23;
      f32x2 t0, t1;
      t0.x = __builtin_amdgcn_exp2f(a01.x); t0.y = __builtin_amdgcn_exp2f(a01.y);
      t1.x = __builtin_amdgcn_exp2f(a23.x); t1.y = __builtin_amdgcn_exp2f(a23.y);
      f32x2 p0 = t0 * t0, p1 = t1 * t1;
      f32x2 q0 = p0 * p0, q1 = p1 * p1;
      f32x2 r0v = q0 * q0, r1v = q1 * q1;
      accA += t0 + p0;
      accB += q0 + r0v;
      accA = r0v * r0v + accA;
      accC += t1 + p1;
      accD += q1 + r1v;
      accC = r1v * r1v + accC;
    }
  }
  float lsum = (accA.x + accA.y) + (accB.x + accB.y)
             + (accC.x + accC.y) + (accD.x + accD.y);
  #pragma unroll
  for (int off = 32; off > 0; off >>= 1) lsum += __shfl_xor(lsum, off);
  if (lane == 0) wsum[wave] = lsum;
  __syncthreads();
  if (tid == 0) {
    float tot = wsum[0] + wsum[1] + wsum[2] + wsum[3];
    float sA = (ti < 32) ? 1.f : -1.f;
    float sB = (tj < 32) ? 1.f : -1.f;
    float fac = sA * sB * ((ti == tj) ? 1.f : 2.f);
    ws->part[blockIdx.x] = fac * tot;
  }
}

__global__ __launch_bounds__(256) void k_final(const Ws* __restrict__ ws,
                                               float* __restrict__ out) {
  __shared__ double red[4];
  int tid = threadIdx.x, wave = tid >> 6, lane = tid & 63;
  double s = 0.0;
  for (int i = tid; i < NBLK; i += 256) s += (double)ws->part[i];
  #pragma unroll
  for (int off = 32; off > 0; off >>= 1) s += __shfl_xor(s, off);
  if (lane == 0) red[wave] = s;
  __syncthreads();
  if (tid == 0)
    out[0] = (float)((red[0] + red[1] + red[2] + red[3]) /
                     ((double)BHALF * (double)BHALF));
}

extern "C" void kernel_launch(void* const* d_in, const int* in_sizes, int n_in,
                              void* d_out, int out_size, void* d_ws, size_t ws_size,
                              hipStream_t stream) {
  const float* src = (const float*)d_in[0];
  const float* tgt = (const float*)d_in[1];
  Ws* ws = (Ws*)d_ws;
  float* out = (float*)d_out;

  size_t wsoff = (sizeof(Ws) + 255) & ~(size_t)255;
  size_t need = wsoff + (size_t)NROWS * DDIM * 2;
  bool fast = ws_size >= need;
  unsigned short* tb = fast ? (unsigned short*)((char*)d_ws + wsoff) : nullptr;

  bool coop_ok = false;
  if (fast) {
    int bpc = 0;
    hipError_t qe = hipOccupancyMaxActiveBlocksPerMultiprocessor(&bpc, k_all, 256, 0);
    if (qe == hipSuccess && bpc >= 1) {
      int grid = bpc * 256;
      if (grid > NBLK) grid = NBLK;
      hipMemsetAsync(d_ws, 0, 8224, stream);   // Ssum8 + colsum2
      const float* a0 = src; const float* a1 = tgt;
      Ws* a2 = ws; unsigned short* a3 = tb; float* a4 = out;
      void* args[] = { &a0, &a1, &a2, &a3, &a4 };
      hipError_t le = hipLaunchCooperativeKernel((const void*)k_all, dim3(grid),
                                                 dim3(256), args, 0, stream);
      coop_ok = (le == hipSuccess);
    }
  }
  if (!coop_ok) {
    hipLaunchKernelGGL(k_prep, dim3(256), dim3(256), 0, stream, src, tgt, ws, tb,
                       fast ? 1 : 0);
    hipLaunchKernelGGL(k_bw, dim3(1), dim3(256), 0, stream, ws);
    if (fast)
      hipLaunchKernelGGL((k_main<1>), dim3(NBLK), dim3(256), 0, stream, tb, src, tgt, ws);
    else
      hipLaunchKernelGGL((k_main<0>), dim3(NBLK), dim3(256), 0, stream, tb, src, tgt, ws);
    hipLaunchKernelGGL(k_final, dim3(1), dim3(256), 0, stream, ws, out);
  }
}

// Round 8
// 119.835 us; speedup vs baseline: 1.9956x; 1.9956x over previous
//
#include <hip/hip_runtime.h>

// MMD loss: source (4096,256) fp32, target (4096,256) fp32 -> scalar fp32.
// bandwidth closed form: sum(l2) = 2n*S - 2*||m||^2 (relu effect negligible).
// Structure (r6 skeleton, NO fences, NO memset, NO cooperative launch):
//   k_prep (256 blk): fp32->bf16 tb, sq[], per-block partials Spart/cpart
//   k_bw   (1 blk)  : reduce partials -> coef = log2(e)/(16*bw)
//   k_main (2080 blk x 512 thr): producer/consumer wave-specialized GEMM.
//       waves 0-3: MFMA compute only (no vmem -> no vmcnt drain at barriers)
//       waves 4-7: global_load_lds staging only (drain overlaps compute)
//       double-buffered 128x64 bf16 tiles (64 KB LDS), XOR swizzle (0 confl),
//       packed epilogue K = t+t^2+t^4+t^8+t^16, plain part[] store
//   k_final(1 blk)  : double-precision sum of part[] -> out

#define NROWS 8192
#define BHALF 4096
#define DDIM  256
#define TILE  128
#define NTILE 64
#define NBLK  2080   // NTILE*(NTILE+1)/2

typedef __attribute__((ext_vector_type(8))) short bf16x8;
typedef __attribute__((ext_vector_type(4))) float f32x4;
typedef __attribute__((ext_vector_type(2))) float f32x2;
typedef __attribute__((ext_vector_type(4))) unsigned short u16x4;

struct Ws {
  float coef;
  float Spart[256];
  float cpart[256][256];   // per-block column-sum partials
  float sq[NROWS];
  float part[NBLK];
};

__device__ __forceinline__ unsigned short f2bf(float x) {
  unsigned int u = __builtin_bit_cast(unsigned int, x);
  return (unsigned short)((u + 0x7fffu + ((u >> 16) & 1u)) >> 16);
}

__device__ __forceinline__ const float* row_ptr(const float* src, const float* tgt, int i) {
  return (i < BHALF) ? (src + (size_t)i * DDIM) : (tgt + (size_t)(i - BHALF) * DDIM);
}

// 256 blocks x 256 threads; 8 rows per wave. Plain-store partials.
__global__ __launch_bounds__(256) void k_prep(const float* __restrict__ src,
                                              const float* __restrict__ tgt,
                                              Ws* __restrict__ ws,
                                              unsigned short* __restrict__ tb,
                                              int conv) {
  __shared__ float cls[4][256];
  __shared__ float sred[4];
  int tid = threadIdx.x, wave = tid >> 6, lane = tid & 63;
  int row0 = blockIdx.x * 32 + wave * 8;
  float c0 = 0.f, c1 = 0.f, c2 = 0.f, c3 = 0.f;
  float s[8];
  #pragma unroll
  for (int r = 0; r < 8; ++r) {
    const float4* rp = (const float4*)row_ptr(src, tgt, row0 + r);
    float4 x = rp[lane];
    if (conv) {
      u16x4 b = { f2bf(x.x), f2bf(x.y), f2bf(x.z), f2bf(x.w) };
      *(u16x4*)&tb[(size_t)(row0 + r) * DDIM + lane * 4] = b;
    }
    c0 += x.x; c1 += x.y; c2 += x.z; c3 += x.w;
    s[r] = x.x * x.x + x.y * x.y + x.z * x.z + x.w * x.w;
  }
  #pragma unroll
  for (int off = 32; off > 0; off >>= 1) {
    #pragma unroll
    for (int r = 0; r < 8; ++r) s[r] += __shfl_xor(s[r], off);
  }
  if (lane == 0) {
    float Sw = 0.f;
    #pragma unroll
    for (int r = 0; r < 8; ++r) { ws->sq[row0 + r] = s[r]; Sw += s[r]; }
    sred[wave] = Sw;
  }
  cls[wave][lane * 4 + 0] = c0;
  cls[wave][lane * 4 + 1] = c1;
  cls[wave][lane * 4 + 2] = c2;
  cls[wave][lane * 4 + 3] = c3;
  __syncthreads();
  ws->cpart[blockIdx.x][tid] = cls[0][tid] + cls[1][tid] + cls[2][tid] + cls[3][tid];
  if (tid == 0) ws->Spart[blockIdx.x] = sred[0] + sred[1] + sred[2] + sred[3];
}

// 1 block x 256 threads: partials -> coef.
__global__ __launch_bounds__(256) void k_bw(Ws* __restrict__ ws) {
  __shared__ float redm[4], reds[4];
  int tid = threadIdx.x, wave = tid >> 6, lane = tid & 63;
  float mc = 0.f;
  for (int b = 0; b < 256; ++b) mc += ws->cpart[b][tid];
  float p = mc * mc;
  float sp = ws->Spart[tid];
  #pragma unroll
  for (int off = 32; off > 0; off >>= 1) {
    p  += __shfl_xor(p, off);
    sp += __shfl_xor(sp, off);
  }
  if (lane == 0) { redm[wave] = p; reds[wave] = sp; }
  __syncthreads();
  if (tid == 0) {
    float msq = redm[0] + redm[1] + redm[2] + redm[3];
    float S   = reds[0] + reds[1] + reds[2] + reds[3];
    double n = (double)NROWS;
    double sum_l2 = 2.0 * n * (double)S - 2.0 * (double)msq;
    double bwv = sum_l2 / (n * n - n) / 4.0;     // / KERNEL_MUL^(KERNEL_NUM/2)
    ws->coef = (float)(1.4426950408889634 / (16.0 * bwv)); // log2(e)/(16*bw)
  }
}

__device__ __forceinline__ void stage_panel(const unsigned short* g,
                                            unsigned short* l, int kc) {
  #pragma unroll
  for (int t = 0; t < 4; ++t)
    __builtin_amdgcn_global_load_lds(
        (const __attribute__((address_space(1))) void*)(g + (size_t)(t * 8) * DDIM + kc * 64),
        (__attribute__((address_space(3))) void*)(l + (t * 8) * 64), 16, 0, 0);
}

// NBLK triangular blocks, 512 thr = 4 compute waves + 4 producer waves.
// Double-buffered 128x64 tiles; exactly 64 KB LDS (wsum aliased into As).
template <int FAST>
__global__ __launch_bounds__(512, 4) void k_main(const unsigned short* __restrict__ tb,
                                                 const float* __restrict__ src,
                                                 const float* __restrict__ tgt,
                                                 Ws* __restrict__ ws) {
  int idx = blockIdx.x;
  int ti = (int)((129.0 - sqrt(129.0 * 129.0 - 8.0 * (double)idx)) * 0.5);
  while (64 * (ti + 1) - ((ti + 1) * ti) / 2 <= idx) ++ti;
  while (64 * ti - (ti * (ti - 1)) / 2 > idx) --ti;
  int tj = ti + (idx - (64 * ti - (ti * (ti - 1)) / 2));

  __shared__ __align__(16) unsigned short As[2][TILE * 64];
  __shared__ __align__(16) unsigned short Bs[2][TILE * 64];

  int tid = threadIdx.x;
  int wave = tid >> 6, lane = tid & 63;
  bool producer = wave >= 4;
  int Ib = ti * TILE, Jb = tj * TILE;

  // ---- consumer state ----
  int wm = (wave >> 1) & 1, wn = wave & 1;     // 2x2 wave grid, 64x64 each
  int lr = lane & 15, q = lane >> 4;
  float coef = 0.f, coef2 = 0.f;
  float nscj[4];
  f32x2 nsci01[4], nsci23[4];
  f32x4 acc[4][4];
  if (!producer) {
    coef = ws->coef;
    coef2 = 2.f * coef;
    int ibase = Ib + wm * 64;
    int jbase = Jb + wn * 64;
    #pragma unroll
    for (int n = 0; n < 4; ++n) nscj[n] = -ws->sq[jbase + n * 16 + lr] * coef;
    #pragma unroll
    for (int m = 0; m < 4; ++m) {
      nsci01[m] = f32x2{ -ws->sq[ibase + m * 16 + q * 4 + 0] * coef,
                         -ws->sq[ibase + m * 16 + q * 4 + 1] * coef };
      nsci23[m] = f32x2{ -ws->sq[ibase + m * 16 + q * 4 + 2] * coef,
                         -ws->sq[ibase + m * 16 + q * 4 + 3] * coef };
    }
    f32x4 zero = {0.f, 0.f, 0.f, 0.f};
    #pragma unroll
    for (int m = 0; m < 4; ++m)
      #pragma unroll
      for (int n = 0; n < 4; ++n) acc[m][n] = zero;
  }

  // ---- producer state ----
  const unsigned short* gA = nullptr; const unsigned short* gB = nullptr;
  int pw = wave - 4;                           // 0..3: 32-row panel each
  if (FAST && producer) {
    int lrow = lane >> 3;                      // 0..7
    int lchk = (lane & 7) ^ lrow;              // XOR-swizzled source chunk
    gA = tb + (size_t)(Ib + pw * 32 + lrow) * DDIM + lchk * 8;
    gB = tb + (size_t)(Jb + pw * 32 + lrow) * DDIM + lchk * 8;
  }
  int ptid = tid - 256;                        // slow-path staging coords
  int r0 = ptid >> 4, c4 = ptid & 15;

  // initial fill: buf0, chunk 0
  if (producer) {
    if (FAST) {
      stage_panel(gA, &As[0][(pw * 32) * 64], 0);
      stage_panel(gB, &Bs[0][(pw * 32) * 64], 0);
    } else {
      #pragma unroll
      for (int rr = 0; rr < 8; ++rr) {
        int row = rr * 16 + r0;
        int sw = ((c4 >> 1) ^ (row & 7)) * 8 + (c4 & 1) * 4;
        float4 va = ((const float4*)row_ptr(src, tgt, Ib + row))[c4];
        u16x4 ba = { f2bf(va.x), f2bf(va.y), f2bf(va.z), f2bf(va.w) };
        *(u16x4*)&As[0][row * 64 + sw] = ba;
        float4 vb = ((const float4*)row_ptr(src, tgt, Jb + row))[c4];
        u16x4 bb = { f2bf(vb.x), f2bf(vb.y), f2bf(vb.z), f2bf(vb.w) };
        *(u16x4*)&Bs[0][row * 64 + sw] = bb;
      }
    }
  }
  __syncthreads();                             // buf0 ready (producer drain)

  #pragma unroll
  for (int kc = 0; kc < 4; ++kc) {
    int cur = kc & 1;
    if (producer) {
      if (kc < 3) {                            // stage next chunk into other buf
        int nxt = cur ^ 1;
        if (FAST) {
          stage_panel(gA, &As[nxt][(pw * 32) * 64], kc + 1);
          stage_panel(gB, &Bs[nxt][(pw * 32) * 64], kc + 1);
        } else {
          #pragma unroll
          for (int rr = 0; rr < 8; ++rr) {
            int row = rr * 16 + r0;
            int sw = ((c4 >> 1) ^ (row & 7)) * 8 + (c4 & 1) * 4;
            float4 va = ((const float4*)row_ptr(src, tgt, Ib + row))[(kc + 1) * 16 + c4];
            u16x4 ba = { f2bf(va.x), f2bf(va.y), f2bf(va.z), f2bf(va.w) };
            *(u16x4*)&As[nxt][row * 64 + sw] = ba;
            float4 vb = ((const float4*)row_ptr(src, tgt, Jb + row))[(kc + 1) * 16 + c4];
            u16x4 bb = { f2bf(vb.x), f2bf(vb.y), f2bf(vb.z), f2bf(vb.w) };
            *(u16x4*)&Bs[nxt][row * 64 + sw] = bb;
          }
        }
      }
    } else {
      #pragma unroll
      for (int kk = 0; kk < 2; ++kk) {
        int cidx = ((kk * 4 + q) ^ (lr & 7)) << 3;   // swizzled chunk offset
        bf16x8 af[4], bfr[4];
        #pragma unroll
        for (int m = 0; m < 4; ++m)
          af[m] = *(const bf16x8*)&As[cur][(wm * 64 + m * 16 + lr) * 64 + cidx];
        #pragma unroll
        for (int n = 0; n < 4; ++n)
          bfr[n] = *(const bf16x8*)&Bs[cur][(wn * 64 + n * 16 + lr) * 64 + cidx];
        #pragma unroll
        for (int m = 0; m < 4; ++m)
          #pragma unroll
          for (int n = 0; n < 4; ++n)
            acc[m][n] = __builtin_amdgcn_mfma_f32_16x16x32_bf16(af[m], bfr[n], acc[m][n], 0, 0, 0);
      }
    }
    __syncthreads();   // consumers done with cur; producers drained into nxt
  }

  // Epilogue (consumers): arg = 2g*coef - (sqi+sqj)*coef; K = t+..+t^16.
  float* wsum = (float*)As;                    // LDS alias (As free after loop)
  if (!producer) {
    const f32x2 c2v = { coef2, coef2 };
    f32x2 accA = {0.f, 0.f}, accB = {0.f, 0.f};
    f32x2 accC = {0.f, 0.f}, accD = {0.f, 0.f};
    #pragma unroll
    for (int m = 0; m < 4; ++m) {
      #pragma unroll
      for (int n = 0; n < 4; ++n) {
        f32x4 g = acc[m][n];
        f32x2 bj = { nscj[n], nscj[n] };
        f32x2 b01 = nsci01[m] + bj;
        f32x2 b23 = nsci23[m] + bj;
        f32x2 a01 = f32x2{g[0], g[1]} * c2v + b01;
        f32x2 a23 = f32x2{g[2], g[3]} * c2v + b23;
        f32x2 t0, t1;
        t0.x = __builtin_amdgcn_exp2f(a01.x); t0.y = __builtin_amdgcn_exp2f(a01.y);
        t1.x = __builtin_amdgcn_exp2f(a23.x); t1.y = __builtin_amdgcn_exp2f(a23.y);
        f32x2 p0 = t0 * t0, p1 = t1 * t1;
        f32x2 q0 = p0 * p0, q1 = p1 * p1;
        f32x2 r0v = q0 * q0, r1v = q1 * q1;
        accA += t0 + p0;
        accB += q0 + r0v;
        accA = r0v * r0v + accA;               // + t^16
        accC += t1 + p1;
        accD += q1 + r1v;
        accC = r1v * r1v + accC;
      }
    }
    float lsum = (accA.x + accA.y) + (accB.x + accB.y)
               + (accC.x + accC.y) + (accD.x + accD.y);
    #pragma unroll
    for (int off = 32; off > 0; off >>= 1) lsum += __shfl_xor(lsum, off);
    if (lane == 0) wsum[wave] = lsum;
  }
  __syncthreads();
  if (tid == 0) {
    float tot = wsum[0] + wsum[1] + wsum[2] + wsum[3];
    float sA = (ti < 32) ? 1.f : -1.f;         // B=4096 = 32 tiles of 128
    float sB = (tj < 32) ? 1.f : -1.f;
    float fac = sA * sB * ((ti == tj) ? 1.f : 2.f);
    ws->part[blockIdx.x] = fac * tot;          // plain store — NO fence/atomic
  }
}

// 1 block x 256 threads: double-precision reduce of part[] -> out scalar.
__global__ __launch_bounds__(256) void k_final(const Ws* __restrict__ ws,
                                               float* __restrict__ out) {
  __shared__ double red[4];
  int tid = threadIdx.x, wave = tid >> 6, lane = tid & 63;
  double s = 0.0;
  for (int i = tid; i < NBLK; i += 256) s += (double)ws->part[i];
  #pragma unroll
  for (int off = 32; off > 0; off >>= 1) s += __shfl_xor(s, off);
  if (lane == 0) red[wave] = s;
  __syncthreads();
  if (tid == 0)
    out[0] = (float)((red[0] + red[1] + red[2] + red[3]) /
                     ((double)BHALF * (double)BHALF));
}

extern "C" void kernel_launch(void* const* d_in, const int* in_sizes, int n_in,
                              void* d_out, int out_size, void* d_ws, size_t ws_size,
                              hipStream_t stream) {
  const float* src = (const float*)d_in[0];
  const float* tgt = (const float*)d_in[1];
  Ws* ws = (Ws*)d_ws;
  float* out = (float*)d_out;

  size_t wsoff = (sizeof(Ws) + 255) & ~(size_t)255;
  size_t need = wsoff + (size_t)NROWS * DDIM * 2;
  bool fast = ws_size >= need;
  unsigned short* tb = fast ? (unsigned short*)((char*)d_ws + wsoff) : nullptr;

  hipLaunchKernelGGL(k_prep, dim3(256), dim3(256), 0, stream, src, tgt, ws, tb,
                     fast ? 1 : 0);
  hipLaunchKernelGGL(k_bw, dim3(1), dim3(256), 0, stream, ws);
  if (fast)
    hipLaunchKernelGGL((k_main<1>), dim3(NBLK), dim3(512), 0, stream, tb, src, tgt, ws);
  else
    hipLaunchKernelGGL((k_main<0>), dim3(NBLK), dim3(512), 0, stream, tb, src, tgt, ws);
  hipLaunchKernelGGL(k_final, dim3(1), dim3(256), 0, stream, ws, out);
}

// Round 9
// 112.594 us; speedup vs baseline: 2.1239x; 1.0643x over previous
//
#include <hip/hip_runtime.h>

// MMD loss: source (4096,256) fp32, target (4096,256) fp32 -> scalar fp32.
// bandwidth closed form: sum(l2) = 2n*S - 2*||m||^2 (relu effect negligible).
// Structure (NO fences, NO memset, NO cooperative launch):
//   k_prep (256 blk): fp32->bf16 tb, sq[], per-block partials Spart/cpart
//   k_bw   (1 blk)  : reduce partials -> coef = log2(e)/(16*bw)
//   k_main (2080 blk x 512 thr): producer/consumer wave-specialized GEMM.
//       waves 0-3: MFMA compute only (no vmem -> no vmcnt drain at barriers)
//       waves 4-7: global_load_lds staging only (drain overlaps compute)
//       double-buffered 128x64 bf16 tiles (64 KB LDS), XOR swizzle (0 confl),
//       packed epilogue K = t+t^2+t^4+t^8+t^16, plain part[] store.
//       __launch_bounds__(512) ONLY — r8's (512,4) was interpreted as
//       4 blocks/CU -> 64-VGPR cap -> acc[4][4] spilled (72 MB scratch writes).
//       LDS already caps at 2 blocks/CU; VGPR headroom 256 -> no spill.
//   k_final(1 blk)  : double-precision sum of part[] -> out

#define NROWS 8192
#define BHALF 4096
#define DDIM  256
#define TILE  128
#define NTILE 64
#define NBLK  2080   // NTILE*(NTILE+1)/2

typedef __attribute__((ext_vector_type(8))) short bf16x8;
typedef __attribute__((ext_vector_type(4))) float f32x4;
typedef __attribute__((ext_vector_type(2))) float f32x2;
typedef __attribute__((ext_vector_type(4))) unsigned short u16x4;

struct Ws {
  float coef;
  float Spart[256];
  float cpart[256][256];   // per-block column-sum partials
  float sq[NROWS];
  float part[NBLK];
};

__device__ __forceinline__ unsigned short f2bf(float x) {
  unsigned int u = __builtin_bit_cast(unsigned int, x);
  return (unsigned short)((u + 0x7fffu + ((u >> 16) & 1u)) >> 16);
}

__device__ __forceinline__ const float* row_ptr(const float* src, const float* tgt, int i) {
  return (i < BHALF) ? (src + (size_t)i * DDIM) : (tgt + (size_t)(i - BHALF) * DDIM);
}

// 256 blocks x 256 threads; 8 rows per wave. Plain-store partials.
__global__ __launch_bounds__(256) void k_prep(const float* __restrict__ src,
                                              const float* __restrict__ tgt,
                                              Ws* __restrict__ ws,
                                              unsigned short* __restrict__ tb,
                                              int conv) {
  __shared__ float cls[4][256];
  __shared__ float sred[4];
  int tid = threadIdx.x, wave = tid >> 6, lane = tid & 63;
  int row0 = blockIdx.x * 32 + wave * 8;
  float c0 = 0.f, c1 = 0.f, c2 = 0.f, c3 = 0.f;
  float s[8];
  #pragma unroll
  for (int r = 0; r < 8; ++r) {
    const float4* rp = (const float4*)row_ptr(src, tgt, row0 + r);
    float4 x = rp[lane];
    if (conv) {
      u16x4 b = { f2bf(x.x), f2bf(x.y), f2bf(x.z), f2bf(x.w) };
      *(u16x4*)&tb[(size_t)(row0 + r) * DDIM + lane * 4] = b;
    }
    c0 += x.x; c1 += x.y; c2 += x.z; c3 += x.w;
    s[r] = x.x * x.x + x.y * x.y + x.z * x.z + x.w * x.w;
  }
  #pragma unroll
  for (int off = 32; off > 0; off >>= 1) {
    #pragma unroll
    for (int r = 0; r < 8; ++r) s[r] += __shfl_xor(s[r], off);
  }
  if (lane == 0) {
    float Sw = 0.f;
    #pragma unroll
    for (int r = 0; r < 8; ++r) { ws->sq[row0 + r] = s[r]; Sw += s[r]; }
    sred[wave] = Sw;
  }
  cls[wave][lane * 4 + 0] = c0;
  cls[wave][lane * 4 + 1] = c1;
  cls[wave][lane * 4 + 2] = c2;
  cls[wave][lane * 4 + 3] = c3;
  __syncthreads();
  ws->cpart[blockIdx.x][tid] = cls[0][tid] + cls[1][tid] + cls[2][tid] + cls[3][tid];
  if (tid == 0) ws->Spart[blockIdx.x] = sred[0] + sred[1] + sred[2] + sred[3];
}

// 1 block x 256 threads: partials -> coef.
__global__ __launch_bounds__(256) void k_bw(Ws* __restrict__ ws) {
  __shared__ float redm[4], reds[4];
  int tid = threadIdx.x, wave = tid >> 6, lane = tid & 63;
  float mc = 0.f;
  for (int b = 0; b < 256; ++b) mc += ws->cpart[b][tid];
  float p = mc * mc;
  float sp = ws->Spart[tid];
  #pragma unroll
  for (int off = 32; off > 0; off >>= 1) {
    p  += __shfl_xor(p, off);
    sp += __shfl_xor(sp, off);
  }
  if (lane == 0) { redm[wave] = p; reds[wave] = sp; }
  __syncthreads();
  if (tid == 0) {
    float msq = redm[0] + redm[1] + redm[2] + redm[3];
    float S   = reds[0] + reds[1] + reds[2] + reds[3];
    double n = (double)NROWS;
    double sum_l2 = 2.0 * n * (double)S - 2.0 * (double)msq;
    double bwv = sum_l2 / (n * n - n) / 4.0;     // / KERNEL_MUL^(KERNEL_NUM/2)
    ws->coef = (float)(1.4426950408889634 / (16.0 * bwv)); // log2(e)/(16*bw)
  }
}

__device__ __forceinline__ void stage_panel(const unsigned short* g,
                                            unsigned short* l, int kc) {
  #pragma unroll
  for (int t = 0; t < 4; ++t)
    __builtin_amdgcn_global_load_lds(
        (const __attribute__((address_space(1))) void*)(g + (size_t)(t * 8) * DDIM + kc * 64),
        (__attribute__((address_space(3))) void*)(l + (t * 8) * 64), 16, 0, 0);
}

// NBLK triangular blocks, 512 thr = 4 compute waves + 4 producer waves.
// Double-buffered 128x64 tiles; exactly 64 KB LDS (wsum aliased into As).
// LDS caps occupancy at 2 blocks/CU; do NOT set a min-blocks launch bound
// (r8: (512,4) -> 64-VGPR cap -> accumulator spill, 72 MB scratch traffic).
template <int FAST>
__global__ __launch_bounds__(512) void k_main(const unsigned short* __restrict__ tb,
                                              const float* __restrict__ src,
                                              const float* __restrict__ tgt,
                                              Ws* __restrict__ ws) {
  int idx = blockIdx.x;
  int ti = (int)((129.0 - sqrt(129.0 * 129.0 - 8.0 * (double)idx)) * 0.5);
  while (64 * (ti + 1) - ((ti + 1) * ti) / 2 <= idx) ++ti;
  while (64 * ti - (ti * (ti - 1)) / 2 > idx) --ti;
  int tj = ti + (idx - (64 * ti - (ti * (ti - 1)) / 2));

  __shared__ __align__(16) unsigned short As[2][TILE * 64];
  __shared__ __align__(16) unsigned short Bs[2][TILE * 64];

  int tid = threadIdx.x;
  int wave = tid >> 6, lane = tid & 63;
  bool producer = wave >= 4;
  int Ib = ti * TILE, Jb = tj * TILE;

  // ---- consumer state ----
  int wm = (wave >> 1) & 1, wn = wave & 1;     // 2x2 wave grid, 64x64 each
  int lr = lane & 15, q = lane >> 4;
  float coef = 0.f, coef2 = 0.f;
  float nscj[4];
  f32x2 nsci01[4], nsci23[4];
  f32x4 acc[4][4];
  if (!producer) {
    coef = ws->coef;
    coef2 = 2.f * coef;
    int ibase = Ib + wm * 64;
    int jbase = Jb + wn * 64;
    #pragma unroll
    for (int n = 0; n < 4; ++n) nscj[n] = -ws->sq[jbase + n * 16 + lr] * coef;
    #pragma unroll
    for (int m = 0; m < 4; ++m) {
      nsci01[m] = f32x2{ -ws->sq[ibase + m * 16 + q * 4 + 0] * coef,
                         -ws->sq[ibase + m * 16 + q * 4 + 1] * coef };
      nsci23[m] = f32x2{ -ws->sq[ibase + m * 16 + q * 4 + 2] * coef,
                         -ws->sq[ibase + m * 16 + q * 4 + 3] * coef };
    }
    f32x4 zero = {0.f, 0.f, 0.f, 0.f};
    #pragma unroll
    for (int m = 0; m < 4; ++m)
      #pragma unroll
      for (int n = 0; n < 4; ++n) acc[m][n] = zero;
  }

  // ---- producer state ----
  const unsigned short* gA = nullptr; const unsigned short* gB = nullptr;
  int pw = wave - 4;                           // 0..3: 32-row panel each
  if (FAST && producer) {
    int lrow = lane >> 3;                      // 0..7
    int lchk = (lane & 7) ^ lrow;              // XOR-swizzled source chunk
    gA = tb + (size_t)(Ib + pw * 32 + lrow) * DDIM + lchk * 8;
    gB = tb + (size_t)(Jb + pw * 32 + lrow) * DDIM + lchk * 8;
  }
  int ptid = tid - 256;                        // slow-path staging coords
  int r0 = ptid >> 4, c4 = ptid & 15;

  // initial fill: buf0, chunk 0
  if (producer) {
    if (FAST) {
      stage_panel(gA, &As[0][(pw * 32) * 64], 0);
      stage_panel(gB, &Bs[0][(pw * 32) * 64], 0);
    } else {
      #pragma unroll
      for (int rr = 0; rr < 8; ++rr) {
        int row = rr * 16 + r0;
        int sw = ((c4 >> 1) ^ (row & 7)) * 8 + (c4 & 1) * 4;
        float4 va = ((const float4*)row_ptr(src, tgt, Ib + row))[c4];
        u16x4 ba = { f2bf(va.x), f2bf(va.y), f2bf(va.z), f2bf(va.w) };
        *(u16x4*)&As[0][row * 64 + sw] = ba;
        float4 vb = ((const float4*)row_ptr(src, tgt, Jb + row))[c4];
        u16x4 bb = { f2bf(vb.x), f2bf(vb.y), f2bf(vb.z), f2bf(vb.w) };
        *(u16x4*)&Bs[0][row * 64 + sw] = bb;
      }
    }
  }
  __syncthreads();                             // buf0 ready (producer drain)

  #pragma unroll
  for (int kc = 0; kc < 4; ++kc) {
    int cur = kc & 1;
    if (producer) {
      if (kc < 3) {                            // stage next chunk into other buf
        int nxt = cur ^ 1;
        if (FAST) {
          stage_panel(gA, &As[nxt][(pw * 32) * 64], kc + 1);
          stage_panel(gB, &Bs[nxt][(pw * 32) * 64], kc + 1);
        } else {
          #pragma unroll
          for (int rr = 0; rr < 8; ++rr) {
            int row = rr * 16 + r0;
            int sw = ((c4 >> 1) ^ (row & 7)) * 8 + (c4 & 1) * 4;
            float4 va = ((const float4*)row_ptr(src, tgt, Ib + row))[(kc + 1) * 16 + c4];
            u16x4 ba = { f2bf(va.x), f2bf(va.y), f2bf(va.z), f2bf(va.w) };
            *(u16x4*)&As[nxt][row * 64 + sw] = ba;
            float4 vb = ((const float4*)row_ptr(src, tgt, Jb + row))[(kc + 1) * 16 + c4];
            u16x4 bb = { f2bf(vb.x), f2bf(vb.y), f2bf(vb.z), f2bf(vb.w) };
            *(u16x4*)&Bs[nxt][row * 64 + sw] = bb;
          }
        }
      }
    } else {
      #pragma unroll
      for (int kk = 0; kk < 2; ++kk) {
        int cidx = ((kk * 4 + q) ^ (lr & 7)) << 3;   // swizzled chunk offset
        bf16x8 af[4], bfr[4];
        #pragma unroll
        for (int m = 0; m < 4; ++m)
          af[m] = *(const bf16x8*)&As[cur][(wm * 64 + m * 16 + lr) * 64 + cidx];
        #pragma unroll
        for (int n = 0; n < 4; ++n)
          bfr[n] = *(const bf16x8*)&Bs[cur][(wn * 64 + n * 16 + lr) * 64 + cidx];
        #pragma unroll
        for (int m = 0; m < 4; ++m)
          #pragma unroll
          for (int n = 0; n < 4; ++n)
            acc[m][n] = __builtin_amdgcn_mfma_f32_16x16x32_bf16(af[m], bfr[n], acc[m][n], 0, 0, 0);
      }
    }
    __syncthreads();   // consumers done with cur; producers drained into nxt
  }

  // Epilogue (consumers): arg = 2g*coef - (sqi+sqj)*coef; K = t+..+t^16.
  float* wsum = (float*)As;                    // LDS alias (As free after loop)
  if (!producer) {
    const f32x2 c2v = { coef2, coef2 };
    f32x2 accA = {0.f, 0.f}, accB = {0.f, 0.f};
    f32x2 accC = {0.f, 0.f}, accD = {0.f, 0.f};
    #pragma unroll
    for (int m = 0; m < 4; ++m) {
      #pragma unroll
      for (int n = 0; n < 4; ++n) {
        f32x4 g = acc[m][n];
        f32x2 bj = { nscj[n], nscj[n] };
        f32x2 b01 = nsci01[m] + bj;
        f32x2 b23 = nsci23[m] + bj;
        f32x2 a01 = f32x2{g[0], g[1]} * c2v + b01;
        f32x2 a23 = f32x2{g[2], g[3]} * c2v + b23;
        f32x2 t0, t1;
        t0.x = __builtin_amdgcn_exp2f(a01.x); t0.y = __builtin_amdgcn_exp2f(a01.y);
        t1.x = __builtin_amdgcn_exp2f(a23.x); t1.y = __builtin_amdgcn_exp2f(a23.y);
        f32x2 p0 = t0 * t0, p1 = t1 * t1;
        f32x2 q0 = p0 * p0, q1 = p1 * p1;
        f32x2 r0v = q0 * q0, r1v = q1 * q1;
        accA += t0 + p0;
        accB += q0 + r0v;
        accA = r0v * r0v + accA;               // + t^16
        accC += t1 + p1;
        accD += q1 + r1v;
        accC = r1v * r1v + accC;
      }
    }
    float lsum = (accA.x + accA.y) + (accB.x + accB.y)
               + (accC.x + accC.y) + (accD.x + accD.y);
    #pragma unroll
    for (int off = 32; off > 0; off >>= 1) lsum += __shfl_xor(lsum, off);
    if (lane == 0) wsum[wave] = lsum;
  }
  __syncthreads();
  if (tid == 0) {
    float tot = wsum[0] + wsum[1] + wsum[2] + wsum[3];
    float sA = (ti < 32) ? 1.f : -1.f;         // B=4096 = 32 tiles of 128
    float sB = (tj < 32) ? 1.f : -1.f;
    float fac = sA * sB * ((ti == tj) ? 1.f : 2.f);
    ws->part[blockIdx.x] = fac * tot;          // plain store — NO fence/atomic
  }
}

// 1 block x 256 threads: double-precision reduce of part[] -> out scalar.
__global__ __launch_bounds__(256) void k_final(const Ws* __restrict__ ws,
                                               float* __restrict__ out) {
  __shared__ double red[4];
  int tid = threadIdx.x, wave = tid >> 6, lane = tid & 63;
  double s = 0.0;
  for (int i = tid; i < NBLK; i += 256) s += (double)ws->part[i];
  #pragma unroll
  for (int off = 32; off > 0; off >>= 1) s += __shfl_xor(s, off);
  if (lane == 0) red[wave] = s;
  __syncthreads();
  if (tid == 0)
    out[0] = (float)((red[0] + red[1] + red[2] + red[3]) /
                     ((double)BHALF * (double)BHALF));
}

extern "C" void kernel_launch(void* const* d_in, const int* in_sizes, int n_in,
                              void* d_out, int out_size, void* d_ws, size_t ws_size,
                              hipStream_t stream) {
  const float* src = (const float*)d_in[0];
  const float* tgt = (const float*)d_in[1];
  Ws* ws = (Ws*)d_ws;
  float* out = (float*)d_out;

  size_t wsoff = (sizeof(Ws) + 255) & ~(size_t)255;
  size_t need = wsoff + (size_t)NROWS * DDIM * 2;
  bool fast = ws_size >= need;
  unsigned short* tb = fast ? (unsigned short*)((char*)d_ws + wsoff) : nullptr;

  hipLaunchKernelGGL(k_prep, dim3(256), dim3(256), 0, stream, src, tgt, ws, tb,
                     fast ? 1 : 0);
  hipLaunchKernelGGL(k_bw, dim3(1), dim3(256), 0, stream, ws);
  if (fast)
    hipLaunchKernelGGL((k_main<1>), dim3(NBLK), dim3(512), 0, stream, tb, src, tgt, ws);
  else
    hipLaunchKernelGGL((k_main<0>), dim3(NBLK), dim3(512), 0, stream, tb, src, tgt, ws);
  hipLaunchKernelGGL(k_final, dim3(1), dim3(256), 0, stream, ws, out);
}